// Round 17
// baseline (122.681 us; speedup 1.0000x reference)
//
#include <hip/hip_runtime.h>

#define LOG2E 1.4426950408889634f

constexpr int D     = 2048;
constexpr int NB    = 16;       // train buffer rows (= MFMA N)
constexpr int TPB   = 256;      // 4 INDEPENDENT waves; no barriers, no LDS
constexpr int NROWS = 16384;    // B*T
constexpr int RPW   = 4;        // rows per wave (A rows 4-15 duplicate 0-3)
constexpr int NBLK  = NROWS / (RPW * 4);   // 1024 blocks
constexpr int NKT   = 64;       // full K per wave: 64 x (16x16x32)

typedef short bf16x8 __attribute__((ext_vector_type(8)));
typedef float f32x4  __attribute__((ext_vector_type(4)));

__device__ __forceinline__ float gelu_tanh_f(float x) {
    const float C = 0.7978845608028654f;   // sqrt(2/pi)
    const float K = 0.044715f;
    float x2 = x * x;
    float p  = __builtin_fmaf(K, x2, 1.0f);
    float z  = C * x * p;                   // c*(x + K x^3)
    float e  = __builtin_amdgcn_exp2f(z * (2.0f * LOG2E));
    float th = 1.0f - 2.0f * __builtin_amdgcn_rcpf(e + 1.0f);
    float hx = 0.5f * x;
    return __builtin_fmaf(hx, th, hx);      // 0.5x(1+tanh)
}

// round-to-nearest-even f32->bf16, packed pair (a=low16, b=high16)
__device__ __forceinline__ unsigned bpack(float a, float b) {
    unsigned ua = __builtin_bit_cast(unsigned, a);
    unsigned ub = __builtin_bit_cast(unsigned, b);
    ua += 0x7FFFu + ((ua >> 16) & 1u);
    ub += 0x7FFFu + ((ub >> 16) & 1u);
    return (ua >> 16) | (ub & 0xFFFF0000u);
}

// ---- pre-pass: buf (16x2048 f32) -> bf16 MFMA B-fragment image in d_ws ----
// dword id -> element n = (id>>2)&15, k = (id>>8)*32 + ((id>>6)&3)*8 + (id&3)*2
// (mapping empirically verified in R7-R16)
__global__ void __launch_bounds__(512) bfrag_kernel(
    const float* __restrict__ buf, unsigned* __restrict__ bfrag)
{
    const int id = blockIdx.x * 512 + threadIdx.x;
    const int n  = (id >> 2) & 15;
    const int k  = ((id >> 8) << 5) + (((id >> 6) & 3) << 3) + ((id & 3) << 1);
    const float* p = buf + n * D + k;
    bfrag[id] = bpack(p[0], p[1]);
}

// Zero-barrier, zero-LDS fused kernel. Each wave owns 4 rows end-to-end:
// A-fragments are gelu'd in-register from direct (4-line) global loads, the
// mod-4 row duplication makes every lane hold all 4 row-dots after its own
// 64 MFMAs, and gates finish with in-wave shuffles only. Nothing in the
// kernel ever waits on another wave -> the x/out streams never stall on a
// phase boundary (the R11-R16 54%-duty plateau).
__global__ void __launch_bounds__(TPB) gelu_gate_kernel(
    const float* __restrict__ x,
    const unsigned* __restrict__ bfrag,   // 16384 dwords, L1/L2-resident
    const int* __restrict__ mask_i,
    const unsigned char* __restrict__ mask_b,
    const float* __restrict__ p_log_tau,
    const float* __restrict__ p_log_blend,
    float* __restrict__ out)
{
    const int t    = threadIdx.x;
    const int lane = t & 63;
    const int wv   = t >> 6;

    const int row0 = (blockIdx.x * 4 + wv) * RPW;   // this wave's 4 rows

    const float tau   = __builtin_amdgcn_exp2f(p_log_tau[0] * LOG2E);
    const float lbt   = p_log_blend[0];
    const float alpha = __builtin_amdgcn_rcpf(1.0f + __builtin_amdgcn_exp2f(-lbt * LOG2E));

    // bool dtype layout ambiguous (u8 vs i32) -> accept either (all-true dataset)
    unsigned mbits = 0;
#pragma unroll
    for (int k = 0; k < NB; ++k) {
        bool mk = (mask_i[k] != 0) || (mask_b[k] != 0);
        mbits |= (mk ? 1u : 0u) << k;
    }

    const int n    = lane & 15;     // C col (buf row) this lane owns
    const int mr   = lane & 3;      // real x-row this lane's A-fragment feeds
    const int kgrp = lane >> 4;     // k-subgroup within a 32-wide k-tile

    const float*    xA = x + (size_t)(row0 + mr) * D + kgrp * 8;
    const unsigned* Bb = bfrag + lane * 4;

    // ---- pass 1: 64 k-tiles of {direct load -> gelu -> pack -> MFMA} ----
    // Two independent acc chains halve the MFMA dependency depth.
    f32x4 acc0 = {0.f, 0.f, 0.f, 0.f};
    f32x4 acc1 = {0.f, 0.f, 0.f, 0.f};
    float p2 = 0.f;

#pragma unroll 4
    for (int kt = 0; kt < NKT; ++kt) {
        const float4 a = *reinterpret_cast<const float4*>(xA + kt * 32);
        const float4 b = *reinterpret_cast<const float4*>(xA + kt * 32 + 4);
        const uint4 bq = *reinterpret_cast<const uint4*>(Bb + kt * 256);
        float y0 = gelu_tanh_f(a.x), y1 = gelu_tanh_f(a.y);
        float y2 = gelu_tanh_f(a.z), y3 = gelu_tanh_f(a.w);
        float y4 = gelu_tanh_f(b.x), y5 = gelu_tanh_f(b.y);
        float y6 = gelu_tanh_f(b.z), y7 = gelu_tanh_f(b.w);
        p2 = __builtin_fmaf(y0, y0, p2); p2 = __builtin_fmaf(y1, y1, p2);
        p2 = __builtin_fmaf(y2, y2, p2); p2 = __builtin_fmaf(y3, y3, p2);
        p2 = __builtin_fmaf(y4, y4, p2); p2 = __builtin_fmaf(y5, y5, p2);
        p2 = __builtin_fmaf(y6, y6, p2); p2 = __builtin_fmaf(y7, y7, p2);
        uint4 yp;
        yp.x = bpack(y0, y1); yp.y = bpack(y2, y3);
        yp.z = bpack(y4, y5); yp.w = bpack(y6, y7);
        if (kt & 1)
            acc1 = __builtin_amdgcn_mfma_f32_16x16x32_bf16(
                __builtin_bit_cast(bf16x8, yp), __builtin_bit_cast(bf16x8, bq),
                acc1, 0, 0, 0);
        else
            acc0 = __builtin_amdgcn_mfma_f32_16x16x32_bf16(
                __builtin_bit_cast(bf16x8, yp), __builtin_bit_cast(bf16x8, bq),
                acc0, 0, 0, 0);
    }
    const f32x4 acc = acc0 + acc1;   // reg j = dot(y[row j], buf[n]), ALL lanes

    // ---- in-wave ||y||^2: reduce over the 16-lane dup-orbit (bits 2-5),
    // each column counted 4x -> scale by 1/4. Lane ends with s2 of row lane&3.
    p2 += __shfl_xor(p2, 4, 64);
    p2 += __shfl_xor(p2, 8, 64);
    p2 += __shfl_xor(p2, 16, 64);
    p2 += __shfl_xor(p2, 32, 64);
    const float s2m = p2 * 0.25f;

    // ---- gates: entirely in registers, every lane gets all 4 ----
    float gate[4];
#pragma unroll
    for (int j = 0; j < 4; ++j) {
        const float s2j = __shfl(s2m, (lane & 60) | j, 64);
        const float inv = __builtin_amdgcn_rcpf(fmaxf(__builtin_sqrtf(s2j), 1e-12f));
        float s = acc[j] * inv;              // sim(row j, buf n)
        if (!((mbits >> n) & 1u)) s = -1.0f;
        s = fmaxf(s, __shfl_xor(s, 1, 64));  // max over n (lane bits 0-3)
        s = fmaxf(s, __shfl_xor(s, 2, 64));
        s = fmaxf(s, __shfl_xor(s, 4, 64));
        s = fmaxf(s, __shfl_xor(s, 8, 64));
        gate[j] = __builtin_fmaf(alpha, __builtin_amdgcn_exp2f(-tau * s * LOG2E),
                                 1.0f - alpha);
    }

    // ---- pass 2: dense re-read (L1/L2-warm), recompute gelu in f32, store ----
    const float4* xR = reinterpret_cast<const float4*>(x)   + (size_t)row0 * (D / 4);
    float4*       oR = reinterpret_cast<float4*>(out)       + (size_t)row0 * (D / 4);
#pragma unroll
    for (int r = 0; r < RPW; ++r) {
        const float gr = gate[r];            // compile-time index (rule #20)
        for (int i = 0; i < 8; ++i) {
            const int idx = r * 512 + i * 64 + lane;
            const float4 a = xR[idx];
            float4 o;
            o.x = gelu_tanh_f(a.x) * gr;
            o.y = gelu_tanh_f(a.y) * gr;
            o.z = gelu_tanh_f(a.z) * gr;
            o.w = gelu_tanh_f(a.w) * gr;
            oR[idx] = o;
        }
    }
}

extern "C" void kernel_launch(void* const* d_in, const int* in_sizes, int n_in,
                              void* d_out, int out_size, void* d_ws, size_t ws_size,
                              hipStream_t stream) {
    const float*         x      = (const float*)d_in[0];
    const float*         buf    = (const float*)d_in[1];
    const int*           mask_i = (const int*)d_in[2];
    const unsigned char* mask_b = (const unsigned char*)d_in[2];
    const float*         lt     = (const float*)d_in[3];
    const float*         lb     = (const float*)d_in[4];
    float*               out    = (float*)d_out;
    unsigned*            bfrag  = (unsigned*)d_ws;   // 64 KiB fragment image

    bfrag_kernel<<<32, 512, 0, stream>>>(buf, bfrag);
    gelu_gate_kernel<<<NBLK, TPB, 0, stream>>>(x, bfrag, mask_i, mask_b, lt, lb, out);
}

// Round 18
// 58.538 us; speedup vs baseline: 2.0957x; 2.0957x over previous
//
#include <hip/hip_runtime.h>

#define LOG2E 1.4426950408889634f

constexpr int D     = 2048;
constexpr int NB    = 16;       // train buffer rows (= MFMA N)
constexpr int TPB   = 256;      // 4 waves, each owns a 512-col k-chunk
constexpr int NROWS = 16384;    // B*T
constexpr int RPB   = 4;        // rows per block (A rows 4-15 duplicate 0-3)
constexpr int NBLK  = NROWS / RPB;   // 4096 blocks -> 8 resident/CU
constexpr int NKT   = 16;       // 16x16x32 k-tiles per wave (16*32 = 512 cols)

typedef short bf16x8 __attribute__((ext_vector_type(8)));
typedef float f32x4  __attribute__((ext_vector_type(4)));

// Lean tanh-GELU: y = x - x * rcp(exp2(x * p2(x^2)) + 1)
// where p2(u) = fma(u, 2*C*K*log2e, 2*C*log2e).  7 VALU ops (2 transcendental).
__device__ __forceinline__ float gelu_tanh_f(float x) {
    const float C2L = 2.0f * 0.7978845608028654f * LOG2E;        // 2*C*log2e
    const float K2L = C2L * 0.044715f;                           // 2*C*K*log2e
    float u  = x * x;
    float pp = __builtin_fmaf(u, K2L, C2L);
    float e  = __builtin_amdgcn_exp2f(x * pp);
    float r  = __builtin_amdgcn_rcpf(e + 1.0f);
    return __builtin_fmaf(-x, r, x);      // x*(1 - 1/(e+1)) = 0.5x(1+tanh)
}

// round-to-nearest-even f32->bf16, packed pair (a=low16, b=high16)
__device__ __forceinline__ unsigned bpack(float a, float b) {
    unsigned ua = __builtin_bit_cast(unsigned, a);
    unsigned ub = __builtin_bit_cast(unsigned, b);
    ua += 0x7FFFu + ((ua >> 16) & 1u);
    ub += 0x7FFFu + ((ub >> 16) & 1u);
    return (ua >> 16) | (ub & 0xFFFF0000u);
}
__device__ __forceinline__ float blo(unsigned w) {
    return __builtin_bit_cast(float, w << 16);
}
__device__ __forceinline__ float bhi(unsigned w) {
    return __builtin_bit_cast(float, w & 0xFFFF0000u);
}

// LDS-visibility barrier that does NOT drain vmcnt (verified safe in R16):
// keeps in-flight global loads/stores alive across phase boundaries.
__device__ __forceinline__ void lds_barrier() {
    asm volatile("s_waitcnt lgkmcnt(0)" ::: "memory");
    __builtin_amdgcn_s_barrier();
}

// ---- pre-pass: buf (16x2048 f32) -> bf16 MFMA B-fragment image in d_ws ----
// dword id -> element n = (id>>2)&15, k = (id>>8)*32 + ((id>>6)&3)*8 + (id&3)*2
// (mapping empirically verified in R7-R16)
__global__ void __launch_bounds__(512) bfrag_kernel(
    const float* __restrict__ buf, unsigned* __restrict__ bfrag)
{
    const int id = blockIdx.x * 512 + threadIdx.x;
    const int n  = (id >> 2) & 15;
    const int k  = ((id >> 8) << 5) + (((id >> 6) & 3) << 3) + ((id & 3) << 1);
    const float* p = buf + n * D + k;
    bfrag[id] = bpack(p[0], p[1]);
}

__global__ void __launch_bounds__(TPB) gelu_gate_kernel(
    const float* __restrict__ x,
    const unsigned* __restrict__ bfrag,   // 16384 dwords, L2-resident
    const int* __restrict__ mask_i,
    const unsigned char* __restrict__ mask_b,
    const float* __restrict__ p_log_tau,
    const float* __restrict__ p_log_blend,
    float* __restrict__ out)
{
    // y-tile: 4 rows x 2048 cols bf16 = 16 KiB, XOR-swizzled (byte ^ (row<<6)).
    __shared__ unsigned ldsY[RPB * D / 2];   // 16 KiB
    __shared__ f32x4    ldsAcc[4][16];       // 1 KiB  y.buf^T partials
    __shared__ float    ldsS2[4][4];         // 64 B   ||y||^2 per wave chunk

    const int t    = threadIdx.x;
    const int lane = t & 63;
    const int wk   = t >> 6;             // wave = k-chunk 0..3

    const float tau   = __builtin_amdgcn_exp2f(p_log_tau[0] * LOG2E);
    const float lbt   = p_log_blend[0];
    const float alpha = __builtin_amdgcn_rcpf(1.0f + __builtin_amdgcn_exp2f(-lbt * LOG2E));

    // bool dtype layout ambiguous (u8 vs i32) -> accept either (all-true dataset)
    unsigned mbits = 0;
#pragma unroll
    for (int k = 0; k < NB; ++k) {
        bool mk = (mask_i[k] != 0) || (mask_b[k] != 0);
        mbits |= (mk ? 1u : 0u) << k;
    }

    const int row0 = blockIdx.x * RPB;
    const float4* x4   = reinterpret_cast<const float4*>(x);
    float4*       out4 = reinterpret_cast<float4*>(out);
    char* ldsYb = reinterpret_cast<char*>(ldsY);

    // ---- phase 1: coalesced x load -> gelu -> s2(f32) + bf16 regs + LDS ----
    float4 v[RPB][2];
#pragma unroll
    for (int j = 0; j < RPB; ++j) {
        v[j][0] = x4[(size_t)(row0 + j) * (D / 4) + 2 * t];
        v[j][1] = x4[(size_t)(row0 + j) * (D / 4) + 2 * t + 1];
    }
    uint4 ypk[RPB];     // 16 VGPRs: this thread's y, kept for the store phase
    float p2[RPB];      // per-thread ||y_j||^2 partials (f32, 8 cols each)
#pragma unroll
    for (int j = 0; j < RPB; ++j) {
        float y0 = gelu_tanh_f(v[j][0].x), y1 = gelu_tanh_f(v[j][0].y);
        float y2 = gelu_tanh_f(v[j][0].z), y3 = gelu_tanh_f(v[j][0].w);
        float y4 = gelu_tanh_f(v[j][1].x), y5 = gelu_tanh_f(v[j][1].y);
        float y6 = gelu_tanh_f(v[j][1].z), y7 = gelu_tanh_f(v[j][1].w);
        float s = y0 * y0;
        s = __builtin_fmaf(y1, y1, s); s = __builtin_fmaf(y2, y2, s);
        s = __builtin_fmaf(y3, y3, s); s = __builtin_fmaf(y4, y4, s);
        s = __builtin_fmaf(y5, y5, s); s = __builtin_fmaf(y6, y6, s);
        s = __builtin_fmaf(y7, y7, s);
        p2[j] = s;
        uint4 w;
        w.x = bpack(y0, y1); w.y = bpack(y2, y3);
        w.z = bpack(y4, y5); w.w = bpack(y6, y7);
        ypk[j] = w;
        const int byte = j * 4096 + ((16 * t) ^ (j << 6));
        *reinterpret_cast<uint4*>(ldsYb + byte) = w;
    }
    // 7-shuffle value-halving wave reduce of the 4 row-sums
    {
        const bool b5 = lane & 32, b4 = lane & 16;
        float e0 = (b5 ? p2[2] : p2[0]) + __shfl_xor(b5 ? p2[0] : p2[2], 32, 64);
        float e1 = (b5 ? p2[3] : p2[1]) + __shfl_xor(b5 ? p2[1] : p2[3], 32, 64);
        float f  = (b4 ? e1 : e0) + __shfl_xor(b4 ? e0 : e1, 16, 64);
        f += __shfl_xor(f, 8, 64);
        f += __shfl_xor(f, 4, 64);
        f += __shfl_xor(f, 2, 64);
        f += __shfl_xor(f, 1, 64);           // lane holds wave-sum of row lane>>4
        if ((lane & 15) == 0) ldsS2[wk][lane >> 4] = f;
    }
    lds_barrier();

    // ---- phase 2: per-wave MFMA (dots only) over its 512-col k-chunk ----
    const int m    = lane & 15;          // C col n; A row (rows 4-15 dup 0-3)
    const int mr   = m & 3;              // real x-row
    const int kgrp = lane >> 4;          // 0..3
    const char* aRow = ldsYb + mr * 4096;
    const int swz    = mr << 6;
    const unsigned* Bb = bfrag + wk * (NKT * 256) + lane * 4;

    f32x4 acc = {0.f, 0.f, 0.f, 0.f};
#pragma unroll
    for (int kt = 0; kt < NKT; ++kt) {
        const int off = wk * 1024 + kt * 64 + kgrp * 16;   // bytes within row
        const uint4 af = *reinterpret_cast<const uint4*>(aRow + (off ^ swz));
        const uint4 bq = *reinterpret_cast<const uint4*>(Bb + kt * 256);
        acc = __builtin_amdgcn_mfma_f32_16x16x32_bf16(
            __builtin_bit_cast(bf16x8, af), __builtin_bit_cast(bf16x8, bq),
            acc, 0, 0, 0);
    }

    // C rows duplicate mod 4 -> lanes 0-15 suffice
    if (lane < 16) ldsAcc[wk][lane] = acc;
    lds_barrier();

    // ---- phase 3: combine 4 k-chunks; gates land in registers of EVERY lane ----
    const int n = lane & 15;
    f32x4 dt = ldsAcc[0][n];
#pragma unroll
    for (int w = 1; w < 4; ++w) dt += ldsAcc[w][n];

    float gate[4];
#pragma unroll
    for (int j = 0; j < 4; ++j) {
        const float s2t = ldsS2[0][j] + ldsS2[1][j] + ldsS2[2][j] + ldsS2[3][j];
        const float inv = __builtin_amdgcn_rcpf(fmaxf(__builtin_sqrtf(s2t), 1e-12f));
        float s = dt[j] * inv;               // sim(row j, buf n)
        if (!((mbits >> n) & 1u)) s = -1.0f;
        s = fmaxf(s, __shfl_xor(s, 1, 64));  // max over n (lane bits 0-3)
        s = fmaxf(s, __shfl_xor(s, 2, 64));
        s = fmaxf(s, __shfl_xor(s, 4, 64));
        s = fmaxf(s, __shfl_xor(s, 8, 64));
        gate[j] = __builtin_fmaf(alpha, __builtin_amdgcn_exp2f(-tau * s * LOG2E),
                                 1.0f - alpha);
    }

    // ---- phase 4: store straight from ypk registers (no barrier needed) ----
#pragma unroll
    for (int j = 0; j < RPB; ++j) {
        const uint4 w = ypk[j];
        const float gj = gate[j];
        float4 o1, o2;
        o1.x = blo(w.x) * gj; o1.y = bhi(w.x) * gj;
        o1.z = blo(w.y) * gj; o1.w = bhi(w.y) * gj;
        o2.x = blo(w.z) * gj; o2.y = bhi(w.z) * gj;
        o2.z = blo(w.w) * gj; o2.w = bhi(w.w) * gj;
        out4[(size_t)(row0 + j) * (D / 4) + 2 * t]     = o1;
        out4[(size_t)(row0 + j) * (D / 4) + 2 * t + 1] = o2;
    }
}

extern "C" void kernel_launch(void* const* d_in, const int* in_sizes, int n_in,
                              void* d_out, int out_size, void* d_ws, size_t ws_size,
                              hipStream_t stream) {
    const float*         x      = (const float*)d_in[0];
    const float*         buf    = (const float*)d_in[1];
    const int*           mask_i = (const int*)d_in[2];
    const unsigned char* mask_b = (const unsigned char*)d_in[2];
    const float*         lt     = (const float*)d_in[3];
    const float*         lb     = (const float*)d_in[4];
    float*               out    = (float*)d_out;
    unsigned*            bfrag  = (unsigned*)d_ws;   // 64 KiB fragment image

    bfrag_kernel<<<32, 512, 0, stream>>>(buf, bfrag);
    gelu_gate_kernel<<<NBLK, TPB, 0, stream>>>(x, bfrag, mask_i, mask_b, lt, lb, out);
}